// Round 3
// baseline (2775.394 us; speedup 1.0000x reference)
//
#include <hip/hip_runtime.h>
#include <math.h>

// ---------------------------------------------------------------------------
// Direct conv, stride 1, SAME. One block = 32x8 output tile x ALL OCB output
// channels (acc in VGPRs). Input staged 4 channels per sync round. Up to 4
// channel-concatenated sources (concat never materialized).
// ---------------------------------------------------------------------------
template<int K, int OCB, int ACT>   // ACT: 0=none 1=relu 2=tanh
__global__ __launch_bounds__(256) void conv_k(
    const float* __restrict__ src0, int c0,
    const float* __restrict__ src1, int c1,
    const float* __restrict__ src2, int c2,
    const float* __restrict__ src3, int c3,
    const float* __restrict__ w, const float* __restrict__ bias,
    float* __restrict__ out, int H, int W)
{
    constexpr int TW = 32, TH = 8, P = K / 2;
    constexpr int TLW = TW + K - 1, TLH = TH + K - 1, CB = 4;
    __shared__ float tile[CB][TLH][TLW + 1];

    const int n  = blockIdx.z;
    const int tx = threadIdx.x & 31;
    const int ty = threadIdx.x >> 5;
    const int x0 = blockIdx.x * TW, y0 = blockIdx.y * TH;
    const int Cin = c0 + c1 + c2 + c3;

    float acc[OCB];
#pragma unroll
    for (int i = 0; i < OCB; i++) acc[i] = 0.f;

    int cgbase = 0;
#pragma unroll
    for (int s = 0; s < 4; s++) {
        const float* sp = (s == 0) ? src0 : (s == 1) ? src1 : (s == 2) ? src2 : src3;
        const int    cn = (s == 0) ? c0   : (s == 1) ? c1   : (s == 2) ? c2   : c3;
        for (int cb = 0; cb < cn; cb += CB) {
            const int nch = (cn - cb < CB) ? (cn - cb) : CB;
            __syncthreads();
            for (int idx = threadIdx.x; idx < nch * TLH * TLW; idx += 256) {
                int ch = idx / (TLH * TLW); int rem = idx - ch * (TLH * TLW);
                int r = rem / TLW, cc = rem - r * TLW;
                int gy = y0 + r - P, gx = x0 + cc - P;
                float vv = 0.f;
                if (gy >= 0 && gy < H && gx >= 0 && gx < W)
                    vv = sp[(size_t)(n * cn + cb + ch) * H * W + (size_t)gy * W + gx];
                tile[ch][r][cc] = vv;
            }
            __syncthreads();
            for (int c = 0; c < nch; c++) {
                float v[K * K];
#pragma unroll
                for (int ky = 0; ky < K; ky++)
#pragma unroll
                    for (int kx = 0; kx < K; kx++)
                        v[ky * K + kx] = tile[c][ty + ky][tx + kx];
                const float* wc = w + (size_t)(cgbase + cb + c) * K * K;
#pragma unroll
                for (int oc = 0; oc < OCB; oc++) {
                    const float* wo = wc + (size_t)oc * Cin * K * K;
#pragma unroll
                    for (int t = 0; t < K * K; t++)
                        acc[oc] = fmaf(wo[t], v[t], acc[oc]);
                }
            }
        }
        cgbase += cn;
    }

    const int xx = x0 + tx, yy = y0 + ty;
#pragma unroll
    for (int oc = 0; oc < OCB; oc++) {
        float r = acc[oc] + bias[oc];
        if (ACT == 1) r = fmaxf(r, 0.f);
        if (ACT == 2) r = tanhf(r);
        out[(((size_t)n * OCB + oc) * H + yy) * W + xx] = r;
    }
}

// ---------------------------------------------------------------------------
__global__ __launch_bounds__(256) void pool_k(
    const float* __restrict__ in, float* __restrict__ out, int NC, int H, int W)
{
    int H2 = H >> 1, W2 = W >> 1;
    int total = NC * H2 * W2;
    int idx = blockIdx.x * 256 + threadIdx.x;
    if (idx >= total) return;
    int x = idx % W2; int t = idx / W2; int y = t % H2; int q = t / H2;
    const float* p = in + ((size_t)q * H + 2 * y) * W + 2 * x;
    out[idx] = fmaxf(fmaxf(p[0], p[1]), fmaxf(p[W], p[W + 1]));
}

// ---------------------------------------------------------------------------
__global__ __launch_bounds__(256) void up_k(
    const float* __restrict__ in, float* __restrict__ out, int NC, int Hi, int Wi, int s)
{
    int Ho = Hi * s, Wo = Wi * s;
    int total = NC * Ho * Wo;
    int idx = blockIdx.x * 256 + threadIdx.x;
    if (idx >= total) return;
    int x = idx % Wo; int t = idx / Wo; int y = t % Ho; int q = t / Ho;
    float inv = 1.0f / (float)s;
    float sx = (x + 0.5f) * inv - 0.5f;
    float sy = (y + 0.5f) * inv - 0.5f;
    int ix0 = (int)floorf(sx), iy0 = (int)floorf(sy);
    float fx = sx - ix0, fy = sy - iy0;
    int ix1 = ix0 + 1, iy1 = iy0 + 1;
    ix0 = ix0 < 0 ? 0 : ix0;           iy0 = iy0 < 0 ? 0 : iy0;
    ix1 = ix1 > Wi - 1 ? Wi - 1 : ix1; iy1 = iy1 > Hi - 1 ? Hi - 1 : iy1;
    const float* p = in + (size_t)q * Hi * Wi;
    float v00 = p[(size_t)iy0 * Wi + ix0], v01 = p[(size_t)iy0 * Wi + ix1];
    float v10 = p[(size_t)iy1 * Wi + ix0], v11 = p[(size_t)iy1 * Wi + ix1];
    float top = v00 + fx * (v01 - v00);
    float bot = v10 + fx * (v11 - v10);
    out[idx] = top + fy * (bot - top);
}

// ---------------------------------------------------------------------------
// Wave-parallel double linear scan (horizontal), in-place on x1/x2.
// ---------------------------------------------------------------------------
__device__ __forceinline__ void scan_pair(const float a[8], float x1[8], float x2[8], int lane)
{
    float P = 1.f, Q1 = 0.f, Q2 = 0.f;
#pragma unroll
    for (int j = 0; j < 8; j++) {
        float av = a[j];
        Q1 = fmaf(av, Q1, (1.f - av) * x1[j]);
        Q2 = fmaf(av, Q2, (1.f - av) * x2[j]);
        P *= av;
    }
#pragma unroll
    for (int d = 1; d < 64; d <<= 1) {
        float Pp  = __shfl_up(P,  (unsigned)d);
        float Q1p = __shfl_up(Q1, (unsigned)d);
        float Q2p = __shfl_up(Q2, (unsigned)d);
        if (lane >= d) {
            Q1 = fmaf(P, Q1p, Q1);
            Q2 = fmaf(P, Q2p, Q2);
            P *= Pp;
        }
    }
    float h1in = __shfl_up(Q1, 1u);
    float h2in = __shfl_up(Q2, 1u);
    if (lane == 0) { h1in = 0.f; h2in = 0.f; }
    float s1 = h1in, s2 = h2in;
#pragma unroll
    for (int j = 0; j < 8; j++) {
        float av = a[j];
        s1 = fmaf(av, s1, (1.f - av) * x1[j]);
        s2 = fmaf(av, s2, (1.f - av) * x2[j]);
        x1[j] = s1; x2[j] = s2;
    }
}

// h1=scan(gx1,ms); h2=scan(gx1,rev ms); h5=scan(gx2,h1); h6=scan(gx2,rev h2);
// hm = max(h5,h6). One wave per row; h1/h2 stay in registers.
__global__ __launch_bounds__(256) void scan_h_fused(
    const float* __restrict__ c9, const float* __restrict__ ms,
    float* __restrict__ hm)
{
    int gw   = (blockIdx.x * 256 + threadIdx.x) >> 6;
    int lane = threadIdx.x & 63;
    int y = gw & 511; int nc = gw >> 9; int c = nc & 15; int n = nc >> 4;
    const float* a1row = c9 + ((((size_t)n * 64 + c)      * 512 + y) << 9);
    const float* a2row = c9 + ((((size_t)n * 64 + 32 + c) * 512 + y) << 9);
    const size_t rowoff = (size_t)gw << 9;
    const float* ur = ms + rowoff;
    int t0 = lane << 3;

    float a1[8], a2[8], x1[8], x2[8];
    {
        float4 b0 = *(const float4*)(a1row + t0);
        float4 b1 = *(const float4*)(a1row + t0 + 4);
        a1[0]=b0.x; a1[1]=b0.y; a1[2]=b0.z; a1[3]=b0.w;
        a1[4]=b1.x; a1[5]=b1.y; a1[6]=b1.z; a1[7]=b1.w;
    }
    {
        float4 b0 = *(const float4*)(a2row + t0);
        float4 b1 = *(const float4*)(a2row + t0 + 4);
        a2[0]=b0.x; a2[1]=b0.y; a2[2]=b0.z; a2[3]=b0.w;
        a2[4]=b1.x; a2[5]=b1.y; a2[6]=b1.z; a2[7]=b1.w;
    }
    {
        float4 b0 = *(const float4*)(ur + t0);
        float4 b1 = *(const float4*)(ur + t0 + 4);
        x1[0]=b0.x; x1[1]=b0.y; x1[2]=b0.z; x1[3]=b0.w;
        x1[4]=b1.x; x1[5]=b1.y; x1[6]=b1.z; x1[7]=b1.w;
    }
    {
        float4 r0 = *(const float4*)(ur + (508 - t0));
        float4 r1 = *(const float4*)(ur + (504 - t0));
        x2[0]=r0.w; x2[1]=r0.z; x2[2]=r0.y; x2[3]=r0.x;
        x2[4]=r1.w; x2[5]=r1.z; x2[6]=r1.y; x2[7]=r1.x;
    }

    scan_pair(a1, x1, x2, lane);

    float r[8];
#pragma unroll
    for (int j = 0; j < 8; j++) r[j] = __shfl(x2[7 - j], 63 - lane);

    scan_pair(a2, x1, r, lane);

    float w0[4], w1[4];
#pragma unroll
    for (int j = 0; j < 4; j++) { w0[j] = fmaxf(x1[j], r[j]); w1[j] = fmaxf(x1[j+4], r[j+4]); }
    *(float4*)(hm + rowoff + t0)     = make_float4(w0[0], w0[1], w0[2], w0[3]);
    *(float4*)(hm + rowoff + t0 + 4) = make_float4(w1[0], w1[1], w1[2], w1[3]);
}

// ---------------------------------------------------------------------------
// Segmented vertical scans: 8 segments x 64 rows, 131072 threads per pass.
// Thread id g: x = g&511 (fastest, coalesced), nc = (g>>9)&31, seg = g>>14.
// Chains: h3 = scan(gate_v, ms); h4 = scan(gate_v, rev ms);
//         h7 = scan(gy2, h3);    h8 = scan(gy2, rev h4).
// gate_v row 0 comes from gy1 row 0.
// Summary buffer SB: [P3, Q3, Q4, P7, Q7, P8, Q8] each 131072 floats.
// h3 stored in dead C2; h4 stored in dead gx2 channel slots of C9.
// ---------------------------------------------------------------------------
#define SV_DECODE \
    int g = blockIdx.x * 256 + threadIdx.x; \
    int x = g & 511; int nc = (g >> 9) & 31; int seg = g >> 14; \
    int c = nc & 15; int n = nc >> 4; int ys = seg << 6; (void)c; (void)n;

__global__ __launch_bounds__(256) void sv_a(
    const float* __restrict__ c9, const float* __restrict__ ms, float* __restrict__ SB)
{
    SV_DECODE
    const float* gx1 = c9 + (((size_t)n * 64 + c)      << 18) + x;
    const float* gy1 = c9 + (((size_t)n * 64 + 16 + c) << 18) + x;
    const float* u   = ms + ((size_t)nc << 18) + x;
    float P = 1.f, Q3 = 0.f, Q4 = 0.f;
    for (int i = 0; i < 64; i++) {
        int y = ys + i;
        float g3 = (y == 0) ? gy1[0] : gx1[(size_t)y << 9];
        float uf = u[(size_t)y << 9];
        float ub = u[(size_t)(511 - y) << 9];
        Q3 = fmaf(g3, Q3, (1.f - g3) * uf);
        Q4 = fmaf(g3, Q4, (1.f - g3) * ub);
        P *= g3;
    }
    SB[g] = P; SB[131072 + g] = Q3; SB[262144 + g] = Q4;
}

__global__ __launch_bounds__(256) void sv_b(
    float* __restrict__ c9, const float* __restrict__ ms,
    float* __restrict__ SB, float* __restrict__ h3buf)
{
    SV_DECODE
    const float* gx1 = c9 + (((size_t)n * 64 + c)      << 18) + x;
    const float* gy1 = c9 + (((size_t)n * 64 + 16 + c) << 18) + x;
    const float* gy2 = c9 + (((size_t)n * 64 + 48 + c) << 18) + x;
    float*       h4p = c9 + (((size_t)n * 64 + 32 + c) << 18) + x;
    const float* u   = ms + ((size_t)nc << 18) + x;
    float*       h3p = h3buf + ((size_t)nc << 18) + x;
    int gc = g & 16383;
    float s3 = 0.f, s4 = 0.f;
    for (int j = 0; j < seg; j++) {
        float Pj  = SB[j * 16384 + gc];
        float Q3j = SB[131072 + j * 16384 + gc];
        float Q4j = SB[262144 + j * 16384 + gc];
        s3 = fmaf(Pj, s3, Q3j);
        s4 = fmaf(Pj, s4, Q4j);
    }
    float P7 = 1.f, Q7 = 0.f;
    for (int i = 0; i < 64; i++) {
        int y = ys + i;
        float g3 = (y == 0) ? gy1[0] : gx1[(size_t)y << 9];
        float uf = u[(size_t)y << 9];
        float ub = u[(size_t)(511 - y) << 9];
        s3 = fmaf(g3, s3, (1.f - g3) * uf);
        s4 = fmaf(g3, s4, (1.f - g3) * ub);
        h3p[(size_t)y << 9] = s3;
        h4p[(size_t)y << 9] = s4;
        float g7 = gy2[(size_t)y << 9];
        Q7 = fmaf(g7, Q7, (1.f - g7) * s3);
        P7 *= g7;
    }
    SB[393216 + g] = P7; SB[524288 + g] = Q7;
}

__global__ __launch_bounds__(256) void sv_c(
    const float* __restrict__ c9, const float* __restrict__ h3buf,
    float* __restrict__ SB, float* __restrict__ hm)
{
    SV_DECODE
    const float* gy2 = c9 + (((size_t)n * 64 + 48 + c) << 18) + x;
    const float* h4p = c9 + (((size_t)n * 64 + 32 + c) << 18) + x;
    const float* h3p = h3buf + ((size_t)nc << 18) + x;
    float*       o   = hm + ((size_t)nc << 18) + x;
    int gc = g & 16383;
    float s7 = 0.f;
    for (int j = 0; j < seg; j++) {
        float Pj = SB[393216 + j * 16384 + gc];
        float Qj = SB[524288 + j * 16384 + gc];
        s7 = fmaf(Pj, s7, Qj);
    }
    float P8 = 1.f, Q8 = 0.f;
    for (int i = 0; i < 64; i++) {
        int y = ys + i;
        float g7 = gy2[(size_t)y << 9];
        float hv = h3p[(size_t)y << 9];
        s7 = fmaf(g7, s7, (1.f - g7) * hv);
        o[(size_t)y << 9] = fmaxf(o[(size_t)y << 9], s7);
        float u8 = h4p[(size_t)(511 - y) << 9];
        Q8 = fmaf(g7, Q8, (1.f - g7) * u8);
        P8 *= g7;
    }
    SB[655360 + g] = P8; SB[786432 + g] = Q8;
}

__global__ __launch_bounds__(256) void sv_d(
    const float* __restrict__ c9, const float* __restrict__ SB, float* __restrict__ hm)
{
    SV_DECODE
    const float* gy2 = c9 + (((size_t)n * 64 + 48 + c) << 18) + x;
    const float* h4p = c9 + (((size_t)n * 64 + 32 + c) << 18) + x;
    float*       o   = hm + ((size_t)nc << 18) + x;
    int gc = g & 16383;
    float s8 = 0.f;
    for (int j = 0; j < seg; j++) {
        float Pj = SB[655360 + j * 16384 + gc];
        float Qj = SB[786432 + j * 16384 + gc];
        s8 = fmaf(Pj, s8, Qj);
    }
    for (int i = 0; i < 64; i++) {
        int y = ys + i;
        float g7 = gy2[(size_t)y << 9];
        float u8 = h4p[(size_t)(511 - y) << 9];
        s8 = fmaf(g7, s8, (1.f - g7) * u8);
        o[(size_t)y << 9] = fmaxf(o[(size_t)y << 9], s8);
    }
}

// ---------------------------------------------------------------------------
extern "C" void kernel_launch(void* const* d_in, const int* in_sizes, int n_in,
                              void* d_out, int out_size, void* d_ws, size_t ws_size,
                              hipStream_t stream)
{
    const float* x    = (const float*)d_in[0];
    const float* w_s1 = (const float*)d_in[1];  const float* b_s1 = (const float*)d_in[2];
    const float* w_mc = (const float*)d_in[3];  const float* b_mc = (const float*)d_in[4];
    const float* w2   = (const float*)d_in[5];  const float* b2   = (const float*)d_in[6];
    const float* w3   = (const float*)d_in[7];  const float* b3   = (const float*)d_in[8];
    const float* w4   = (const float*)d_in[9];  const float* b4   = (const float*)d_in[10];
    const float* w5   = (const float*)d_in[11]; const float* b5   = (const float*)d_in[12];
    const float* w6   = (const float*)d_in[13]; const float* b6   = (const float*)d_in[14];
    const float* w6s  = (const float*)d_in[15]; const float* b6s  = (const float*)d_in[16];
    const float* w7   = (const float*)d_in[17]; const float* b7   = (const float*)d_in[18];
    const float* w8   = (const float*)d_in[19]; const float* b8   = (const float*)d_in[20];
    const float* w9   = (const float*)d_in[21]; const float* b9   = (const float*)d_in[22];
    const float* w10  = (const float*)d_in[23]; const float* b10  = (const float*)d_in[24];
    const float* w11  = (const float*)d_in[25]; const float* b11  = (const float*)d_in[26];
    float* out = (float*)d_out;
    float* ws  = (float*)d_ws;

    const size_t NEEDED = 60817408ull * 4ull;   // 232 MiB (fits — verified r2)
    if (ws_size < NEEDED) return;

    float* MS = ws;                    // [2,16,512,512] ms
    float* C2 = ws + 8388608;          // [2,16,512,512] c2 -> later h3
    float* C9 = ws + 16777216;         // [2,64,512,512] gates; gx2 slots -> h4
    float* AR = ws + 50331648;         // arena, 10,485,760 floats
    float* s1 = AR + 0;
    float* s2 = AR + 1572864;
    float* s3 = AR + 1966080;
    float* s4 = AR + 2064384;
    float* u2 = AR + 2088960;
    float* u3 = AR + 3661824;
    float* u4 = AR + 5234688;
    float* p2    = AR + 0;
    float* c3    = AR + 2097152;
    float* p3    = AR + 6291456;
    float* c4    = AR + 7340032;
    float* p4    = AR + 8388608;
    float* c5    = AR + 8650752;
    float* p5    = AR + 8912896;
    float* c6    = AR + 8978432;
    float* u6    = AR + 9109504;
    float* t6    = AR + 0;
    float* c6re  = AR + 8388608;
    float* c7pre = AR + 524288;
    float* c7    = AR + 6291456;
    float* c8pre = AR + 0;
    float* c8    = AR + 2097152;
    float* HM  = AR + 0;
    float* SB  = AR + 8388608;   // 7 x 131072 floats (scan summaries)
    float* H3  = C2;
    float* C10 = C9;

    auto cdiv = [](int a, int b) { return (a + b - 1) / b; };

    // ---- multi-scale branch ----
    conv_k<3,3,0><<<dim3(16,64,2),256,0,stream>>>(x,3,nullptr,0,nullptr,0,nullptr,0,
                                                  w_s1,b_s1, s1, 512,512);
    pool_k<<<cdiv(2*3*256*256,256),256,0,stream>>>(s1, s2, 6, 512, 512);
    pool_k<<<cdiv(2*3*128*128,256),256,0,stream>>>(s2, s3, 6, 256, 256);
    pool_k<<<cdiv(2*3*64*64,  256),256,0,stream>>>(s3, s4, 6, 128, 128);
    up_k<<<cdiv(2*3*512*512,256),256,0,stream>>>(s2, u2, 6, 256, 256, 2);
    up_k<<<cdiv(2*3*512*512,256),256,0,stream>>>(s3, u3, 6, 128, 128, 4);
    up_k<<<cdiv(2*3*512*512,256),256,0,stream>>>(s4, u4, 6, 64, 64, 8);
    conv_k<3,16,0><<<dim3(16,64,2),256,0,stream>>>(s1,3,u2,3,u3,3,u4,3,
                                                   w_mc,b_mc, MS, 512,512);

    // ---- encoder ----
    conv_k<5,16,1><<<dim3(16,64,2),256,0,stream>>>(x,3,nullptr,0,nullptr,0,nullptr,0,
                                                   w2,b2, C2, 512,512);
    pool_k<<<cdiv(2*16*256*256,256),256,0,stream>>>(C2, p2, 32, 512, 512);
    conv_k<3,32,1><<<dim3(8,32,2),256,0,stream>>>(p2,16,nullptr,0,nullptr,0,nullptr,0,
                                                  w3,b3, c3, 256,256);
    pool_k<<<cdiv(2*32*128*128,256),256,0,stream>>>(c3, p3, 64, 256, 256);
    conv_k<3,32,1><<<dim3(4,16,2),256,0,stream>>>(p3,32,nullptr,0,nullptr,0,nullptr,0,
                                                  w4,b4, c4, 128,128);
    pool_k<<<cdiv(2*32*64*64,256),256,0,stream>>>(c4, p4, 64, 128, 128);
    conv_k<3,32,1><<<dim3(2,8,2),256,0,stream>>>(p4,32,nullptr,0,nullptr,0,nullptr,0,
                                                 w5,b5, c5, 64,64);
    pool_k<<<cdiv(2*32*32*32,256),256,0,stream>>>(c5, p5, 64, 64, 64);
    conv_k<3,64,1><<<dim3(1,4,2),256,0,stream>>>(p5,32,nullptr,0,nullptr,0,nullptr,0,
                                                 w6,b6, c6, 32,32);

    // ---- decoder ----
    up_k<<<cdiv(2*64*64*64,256),256,0,stream>>>(c6, u6, 128, 32, 32, 2);
    conv_k<3,64,1><<<dim3(2,8,2),256,0,stream>>>(u6,64,nullptr,0,nullptr,0,nullptr,0,
                                                 w6s,b6s, t6, 64,64);
    up_k<<<cdiv(2*64*128*128,256),256,0,stream>>>(t6, c6re, 128, 64, 64, 2);
    conv_k<3,32,1><<<dim3(4,16,2),256,0,stream>>>(c6re,64,c4,32,nullptr,0,nullptr,0,
                                                  w7,b7, c7pre, 128,128);
    up_k<<<cdiv(2*32*256*256,256),256,0,stream>>>(c7pre, c7, 64, 128, 128, 2);
    conv_k<3,16,1><<<dim3(8,32,2),256,0,stream>>>(c7,32,c3,32,nullptr,0,nullptr,0,
                                                  w8,b8, c8pre, 256,256);
    up_k<<<cdiv(2*16*512*512,256),256,0,stream>>>(c8pre, c8, 32, 256, 256, 2);
    conv_k<3,64,2><<<dim3(16,64,2),256,0,stream>>>(c8,16,C2,16,nullptr,0,nullptr,0,
                                                   w9,b9, C9, 512,512);

    // ---- linear recurrence scans ----
    scan_h_fused<<<4096,256,0,stream>>>(C9, MS, HM);
    sv_a<<<512,256,0,stream>>>(C9, MS, SB);
    sv_b<<<512,256,0,stream>>>(C9, MS, SB, H3);
    sv_c<<<512,256,0,stream>>>(C9, H3, SB, HM);
    sv_d<<<512,256,0,stream>>>(C9, SB, HM);

    // ---- head ----
    conv_k<3,64,1><<<dim3(16,64,2),256,0,stream>>>(HM,16,nullptr,0,nullptr,0,nullptr,0,
                                                   w10,b10, C10, 512,512);
    conv_k<3,3,1><<<dim3(16,64,2),256,0,stream>>>(C10,64,nullptr,0,nullptr,0,nullptr,0,
                                                  w11,b11, out, 512,512);
    (void)in_sizes; (void)n_in; (void)out_size; (void)ws_size;
}

// Round 4
// 1862.404 us; speedup vs baseline: 1.4902x; 1.4902x over previous
//
#include <hip/hip_runtime.h>
#include <math.h>

// ---------------------------------------------------------------------------
// Direct conv, stride 1, SAME. Block = 32x16 output tile; each thread owns
// 2 adjacent y-pixels x OCB output channels (acc in VGPRs, 2*OCB total).
// OC > OCB handled by z-chunking. Input staged 4 channels per sync round.
// Up to 4 channel-concatenated sources (concat never materialized).
// __launch_bounds__(256,4): allow up to 128 VGPR -> no scratch spill (r3 bug).
// ---------------------------------------------------------------------------
template<int K, int OCB, int ACT>   // ACT: 0=none 1=relu 2=tanh
__global__ __launch_bounds__(256, 4) void conv_k(
    const float* __restrict__ src0, int c0,
    const float* __restrict__ src1, int c1,
    const float* __restrict__ src2, int c2,
    const float* __restrict__ src3, int c3,
    const float* __restrict__ w, const float* __restrict__ bias,
    float* __restrict__ out, int H, int W, int OC, int ocChunks)
{
    constexpr int TW = 32, TH = 16, P = K / 2;
    constexpr int TLW = TW + K - 1, TLH = TH + K - 1;
    constexpr int TLWP = (K == 3) ? 36 : 40;   // padded row stride (floats)
    constexpr int CB = 4;
    __shared__ float tile[CB][TLH][TLWP];

    const int z   = blockIdx.z;
    const int n   = z / ocChunks;
    const int ocb = (z - n * ocChunks) * OCB;
    const int tx  = threadIdx.x & 31;
    const int ty  = threadIdx.x >> 5;          // 0..7 -> rows 2*ty, 2*ty+1
    const int x0  = blockIdx.x * TW, y0 = blockIdx.y * TH;
    const int Cin = c0 + c1 + c2 + c3;

    float acc0[OCB], acc1[OCB];
#pragma unroll
    for (int i = 0; i < OCB; i++) { acc0[i] = 0.f; acc1[i] = 0.f; }

    int cgbase = 0;
#pragma unroll
    for (int s = 0; s < 4; s++) {
        const float* sp = (s == 0) ? src0 : (s == 1) ? src1 : (s == 2) ? src2 : src3;
        const int    cn = (s == 0) ? c0   : (s == 1) ? c1   : (s == 2) ? c2   : c3;
        for (int cb = 0; cb < cn; cb += CB) {
            const int nch = (cn - cb < CB) ? (cn - cb) : CB;
            __syncthreads();
            for (int idx = threadIdx.x; idx < nch * TLH * TLW; idx += 256) {
                int ch = idx / (TLH * TLW); int rem = idx - ch * (TLH * TLW);
                int r = rem / TLW, cc = rem - r * TLW;
                int gy = y0 + r - P, gx = x0 + cc - P;
                float vv = 0.f;
                if (gy >= 0 && gy < H && gx >= 0 && gx < W)
                    vv = sp[(size_t)(n * cn + cb + ch) * H * W + (size_t)gy * W + gx];
                tile[ch][r][cc] = vv;
            }
            __syncthreads();
            for (int c = 0; c < nch; c++) {
                // window regs: rows 2ty..2ty+K (K+1 rows), cols tx..tx+K-1
                float v[K + 1][K];
#pragma unroll
                for (int r = 0; r <= K; r++)
#pragma unroll
                    for (int cc = 0; cc < K; cc++)
                        v[r][cc] = tile[c][2 * ty + r][tx + cc];
                const float* wc = w + ((size_t)ocb * Cin + (cgbase + cb + c)) * (K * K);
#pragma unroll
                for (int oc = 0; oc < OCB; oc++) {
                    const float* wo = wc + (size_t)oc * Cin * (K * K);
#pragma unroll
                    for (int ky = 0; ky < K; ky++)
#pragma unroll
                        for (int kx = 0; kx < K; kx++) {
                            float ww = wo[ky * K + kx];
                            acc0[oc] = fmaf(ww, v[ky][kx],     acc0[oc]);
                            acc1[oc] = fmaf(ww, v[ky + 1][kx], acc1[oc]);
                        }
                }
            }
        }
        cgbase += cn;
    }

    const int xx = x0 + tx, yy = y0 + 2 * ty;
#pragma unroll
    for (int oc = 0; oc < OCB; oc++) {
        int o = ocb + oc;
        float b = bias[o];
        float r0 = acc0[oc] + b, r1 = acc1[oc] + b;
        if (ACT == 1) { r0 = fmaxf(r0, 0.f); r1 = fmaxf(r1, 0.f); }
        if (ACT == 2) { r0 = tanhf(r0);      r1 = tanhf(r1); }
        size_t base = (((size_t)n * OC + o) * H + yy) * W + xx;
        out[base]     = r0;
        out[base + W] = r1;
    }
}

// ---------------------------------------------------------------------------
__global__ __launch_bounds__(256) void pool_k(
    const float* __restrict__ in, float* __restrict__ out, int NC, int H, int W)
{
    int H2 = H >> 1, W2 = W >> 1;
    int total = NC * H2 * W2;
    int idx = blockIdx.x * 256 + threadIdx.x;
    if (idx >= total) return;
    int x = idx % W2; int t = idx / W2; int y = t % H2; int q = t / H2;
    const float* p = in + ((size_t)q * H + 2 * y) * W + 2 * x;
    out[idx] = fmaxf(fmaxf(p[0], p[1]), fmaxf(p[W], p[W + 1]));
}

// ---------------------------------------------------------------------------
__global__ __launch_bounds__(256) void up_k(
    const float* __restrict__ in, float* __restrict__ out, int NC, int Hi, int Wi, int s)
{
    int Ho = Hi * s, Wo = Wi * s;
    int total = NC * Ho * Wo;
    int idx = blockIdx.x * 256 + threadIdx.x;
    if (idx >= total) return;
    int x = idx % Wo; int t = idx / Wo; int y = t % Ho; int q = t / Ho;
    float inv = 1.0f / (float)s;
    float sx = (x + 0.5f) * inv - 0.5f;
    float sy = (y + 0.5f) * inv - 0.5f;
    int ix0 = (int)floorf(sx), iy0 = (int)floorf(sy);
    float fx = sx - ix0, fy = sy - iy0;
    int ix1 = ix0 + 1, iy1 = iy0 + 1;
    ix0 = ix0 < 0 ? 0 : ix0;           iy0 = iy0 < 0 ? 0 : iy0;
    ix1 = ix1 > Wi - 1 ? Wi - 1 : ix1; iy1 = iy1 > Hi - 1 ? Hi - 1 : iy1;
    const float* p = in + (size_t)q * Hi * Wi;
    float v00 = p[(size_t)iy0 * Wi + ix0], v01 = p[(size_t)iy0 * Wi + ix1];
    float v10 = p[(size_t)iy1 * Wi + ix0], v11 = p[(size_t)iy1 * Wi + ix1];
    float top = v00 + fx * (v01 - v00);
    float bot = v10 + fx * (v11 - v10);
    out[idx] = top + fy * (bot - top);
}

// ---------------------------------------------------------------------------
// Wave-parallel double linear scan (horizontal), in-place on x1/x2.
// ---------------------------------------------------------------------------
__device__ __forceinline__ void scan_pair(const float a[8], float x1[8], float x2[8], int lane)
{
    float P = 1.f, Q1 = 0.f, Q2 = 0.f;
#pragma unroll
    for (int j = 0; j < 8; j++) {
        float av = a[j];
        Q1 = fmaf(av, Q1, (1.f - av) * x1[j]);
        Q2 = fmaf(av, Q2, (1.f - av) * x2[j]);
        P *= av;
    }
#pragma unroll
    for (int d = 1; d < 64; d <<= 1) {
        float Pp  = __shfl_up(P,  (unsigned)d);
        float Q1p = __shfl_up(Q1, (unsigned)d);
        float Q2p = __shfl_up(Q2, (unsigned)d);
        if (lane >= d) {
            Q1 = fmaf(P, Q1p, Q1);
            Q2 = fmaf(P, Q2p, Q2);
            P *= Pp;
        }
    }
    float h1in = __shfl_up(Q1, 1u);
    float h2in = __shfl_up(Q2, 1u);
    if (lane == 0) { h1in = 0.f; h2in = 0.f; }
    float s1 = h1in, s2 = h2in;
#pragma unroll
    for (int j = 0; j < 8; j++) {
        float av = a[j];
        s1 = fmaf(av, s1, (1.f - av) * x1[j]);
        s2 = fmaf(av, s2, (1.f - av) * x2[j]);
        x1[j] = s1; x2[j] = s2;
    }
}

// h1=scan(gx1,ms); h2=scan(gx1,rev ms); h5=scan(gx2,h1); h6=scan(gx2,rev h2);
// hm = max(h5,h6). One wave per row; h1/h2 stay in registers.
__global__ __launch_bounds__(256) void scan_h_fused(
    const float* __restrict__ c9, const float* __restrict__ ms,
    float* __restrict__ hm)
{
    int gw   = (blockIdx.x * 256 + threadIdx.x) >> 6;
    int lane = threadIdx.x & 63;
    int y = gw & 511; int nc = gw >> 9; int c = nc & 15; int n = nc >> 4;
    const float* a1row = c9 + ((((size_t)n * 64 + c)      * 512 + y) << 9);
    const float* a2row = c9 + ((((size_t)n * 64 + 32 + c) * 512 + y) << 9);
    const size_t rowoff = (size_t)gw << 9;
    const float* ur = ms + rowoff;
    int t0 = lane << 3;

    float a1[8], a2[8], x1[8], x2[8];
    {
        float4 b0 = *(const float4*)(a1row + t0);
        float4 b1 = *(const float4*)(a1row + t0 + 4);
        a1[0]=b0.x; a1[1]=b0.y; a1[2]=b0.z; a1[3]=b0.w;
        a1[4]=b1.x; a1[5]=b1.y; a1[6]=b1.z; a1[7]=b1.w;
    }
    {
        float4 b0 = *(const float4*)(a2row + t0);
        float4 b1 = *(const float4*)(a2row + t0 + 4);
        a2[0]=b0.x; a2[1]=b0.y; a2[2]=b0.z; a2[3]=b0.w;
        a2[4]=b1.x; a2[5]=b1.y; a2[6]=b1.z; a2[7]=b1.w;
    }
    {
        float4 b0 = *(const float4*)(ur + t0);
        float4 b1 = *(const float4*)(ur + t0 + 4);
        x1[0]=b0.x; x1[1]=b0.y; x1[2]=b0.z; x1[3]=b0.w;
        x1[4]=b1.x; x1[5]=b1.y; x1[6]=b1.z; x1[7]=b1.w;
    }
    {
        float4 r0 = *(const float4*)(ur + (508 - t0));
        float4 r1 = *(const float4*)(ur + (504 - t0));
        x2[0]=r0.w; x2[1]=r0.z; x2[2]=r0.y; x2[3]=r0.x;
        x2[4]=r1.w; x2[5]=r1.z; x2[6]=r1.y; x2[7]=r1.x;
    }

    scan_pair(a1, x1, x2, lane);

    float r[8];
#pragma unroll
    for (int j = 0; j < 8; j++) r[j] = __shfl(x2[7 - j], 63 - lane);

    scan_pair(a2, x1, r, lane);

    float w0[4], w1[4];
#pragma unroll
    for (int j = 0; j < 4; j++) { w0[j] = fmaxf(x1[j], r[j]); w1[j] = fmaxf(x1[j+4], r[j+4]); }
    *(float4*)(hm + rowoff + t0)     = make_float4(w0[0], w0[1], w0[2], w0[3]);
    *(float4*)(hm + rowoff + t0 + 4) = make_float4(w1[0], w1[1], w1[2], w1[3]);
}

// ---------------------------------------------------------------------------
// Segmented vertical scans: 8 segments x 64 rows, 131072 threads per pass.
// h3 stored in dead C2; h4 stored in dead gx2 channel slots of C9.
// ---------------------------------------------------------------------------
#define SV_DECODE \
    int g = blockIdx.x * 256 + threadIdx.x; \
    int x = g & 511; int nc = (g >> 9) & 31; int seg = g >> 14; \
    int c = nc & 15; int n = nc >> 4; int ys = seg << 6; (void)c; (void)n;

__global__ __launch_bounds__(256) void sv_a(
    const float* __restrict__ c9, const float* __restrict__ ms, float* __restrict__ SB)
{
    SV_DECODE
    const float* gx1 = c9 + (((size_t)n * 64 + c)      << 18) + x;
    const float* gy1 = c9 + (((size_t)n * 64 + 16 + c) << 18) + x;
    const float* u   = ms + ((size_t)nc << 18) + x;
    float P = 1.f, Q3 = 0.f, Q4 = 0.f;
    for (int i = 0; i < 64; i++) {
        int y = ys + i;
        float g3 = (y == 0) ? gy1[0] : gx1[(size_t)y << 9];
        float uf = u[(size_t)y << 9];
        float ub = u[(size_t)(511 - y) << 9];
        Q3 = fmaf(g3, Q3, (1.f - g3) * uf);
        Q4 = fmaf(g3, Q4, (1.f - g3) * ub);
        P *= g3;
    }
    SB[g] = P; SB[131072 + g] = Q3; SB[262144 + g] = Q4;
}

__global__ __launch_bounds__(256) void sv_b(
    float* __restrict__ c9, const float* __restrict__ ms,
    float* __restrict__ SB, float* __restrict__ h3buf)
{
    SV_DECODE
    const float* gx1 = c9 + (((size_t)n * 64 + c)      << 18) + x;
    const float* gy1 = c9 + (((size_t)n * 64 + 16 + c) << 18) + x;
    const float* gy2 = c9 + (((size_t)n * 64 + 48 + c) << 18) + x;
    float*       h4p = c9 + (((size_t)n * 64 + 32 + c) << 18) + x;
    const float* u   = ms + ((size_t)nc << 18) + x;
    float*       h3p = h3buf + ((size_t)nc << 18) + x;
    int gc = g & 16383;
    float s3 = 0.f, s4 = 0.f;
    for (int j = 0; j < seg; j++) {
        float Pj  = SB[j * 16384 + gc];
        float Q3j = SB[131072 + j * 16384 + gc];
        float Q4j = SB[262144 + j * 16384 + gc];
        s3 = fmaf(Pj, s3, Q3j);
        s4 = fmaf(Pj, s4, Q4j);
    }
    float P7 = 1.f, Q7 = 0.f;
    for (int i = 0; i < 64; i++) {
        int y = ys + i;
        float g3 = (y == 0) ? gy1[0] : gx1[(size_t)y << 9];
        float uf = u[(size_t)y << 9];
        float ub = u[(size_t)(511 - y) << 9];
        s3 = fmaf(g3, s3, (1.f - g3) * uf);
        s4 = fmaf(g3, s4, (1.f - g3) * ub);
        h3p[(size_t)y << 9] = s3;
        h4p[(size_t)y << 9] = s4;
        float g7 = gy2[(size_t)y << 9];
        Q7 = fmaf(g7, Q7, (1.f - g7) * s3);
        P7 *= g7;
    }
    SB[393216 + g] = P7; SB[524288 + g] = Q7;
}

__global__ __launch_bounds__(256) void sv_c(
    const float* __restrict__ c9, const float* __restrict__ h3buf,
    float* __restrict__ SB, float* __restrict__ hm)
{
    SV_DECODE
    const float* gy2 = c9 + (((size_t)n * 64 + 48 + c) << 18) + x;
    const float* h4p = c9 + (((size_t)n * 64 + 32 + c) << 18) + x;
    const float* h3p = h3buf + ((size_t)nc << 18) + x;
    float*       o   = hm + ((size_t)nc << 18) + x;
    int gc = g & 16383;
    float s7 = 0.f;
    for (int j = 0; j < seg; j++) {
        float Pj = SB[393216 + j * 16384 + gc];
        float Qj = SB[524288 + j * 16384 + gc];
        s7 = fmaf(Pj, s7, Qj);
    }
    float P8 = 1.f, Q8 = 0.f;
    for (int i = 0; i < 64; i++) {
        int y = ys + i;
        float g7 = gy2[(size_t)y << 9];
        float hv = h3p[(size_t)y << 9];
        s7 = fmaf(g7, s7, (1.f - g7) * hv);
        o[(size_t)y << 9] = fmaxf(o[(size_t)y << 9], s7);
        float u8 = h4p[(size_t)(511 - y) << 9];
        Q8 = fmaf(g7, Q8, (1.f - g7) * u8);
        P8 *= g7;
    }
    SB[655360 + g] = P8; SB[786432 + g] = Q8;
}

__global__ __launch_bounds__(256) void sv_d(
    const float* __restrict__ c9, const float* __restrict__ SB, float* __restrict__ hm)
{
    SV_DECODE
    const float* gy2 = c9 + (((size_t)n * 64 + 48 + c) << 18) + x;
    const float* h4p = c9 + (((size_t)n * 64 + 32 + c) << 18) + x;
    float*       o   = hm + ((size_t)nc << 18) + x;
    int gc = g & 16383;
    float s8 = 0.f;
    for (int j = 0; j < seg; j++) {
        float Pj = SB[655360 + j * 16384 + gc];
        float Qj = SB[786432 + j * 16384 + gc];
        s8 = fmaf(Pj, s8, Qj);
    }
    for (int i = 0; i < 64; i++) {
        int y = ys + i;
        float g7 = gy2[(size_t)y << 9];
        float u8 = h4p[(size_t)(511 - y) << 9];
        s8 = fmaf(g7, s8, (1.f - g7) * u8);
        o[(size_t)y << 9] = fmaxf(o[(size_t)y << 9], s8);
    }
}

// ---------------------------------------------------------------------------
extern "C" void kernel_launch(void* const* d_in, const int* in_sizes, int n_in,
                              void* d_out, int out_size, void* d_ws, size_t ws_size,
                              hipStream_t stream)
{
    const float* x    = (const float*)d_in[0];
    const float* w_s1 = (const float*)d_in[1];  const float* b_s1 = (const float*)d_in[2];
    const float* w_mc = (const float*)d_in[3];  const float* b_mc = (const float*)d_in[4];
    const float* w2   = (const float*)d_in[5];  const float* b2   = (const float*)d_in[6];
    const float* w3   = (const float*)d_in[7];  const float* b3   = (const float*)d_in[8];
    const float* w4   = (const float*)d_in[9];  const float* b4   = (const float*)d_in[10];
    const float* w5   = (const float*)d_in[11]; const float* b5   = (const float*)d_in[12];
    const float* w6   = (const float*)d_in[13]; const float* b6   = (const float*)d_in[14];
    const float* w6s  = (const float*)d_in[15]; const float* b6s  = (const float*)d_in[16];
    const float* w7   = (const float*)d_in[17]; const float* b7   = (const float*)d_in[18];
    const float* w8   = (const float*)d_in[19]; const float* b8   = (const float*)d_in[20];
    const float* w9   = (const float*)d_in[21]; const float* b9   = (const float*)d_in[22];
    const float* w10  = (const float*)d_in[23]; const float* b10  = (const float*)d_in[24];
    const float* w11  = (const float*)d_in[25]; const float* b11  = (const float*)d_in[26];
    float* out = (float*)d_out;
    float* ws  = (float*)d_ws;

    const size_t NEEDED = 60817408ull * 4ull;   // 232 MiB (fits — verified r2/r3)
    if (ws_size < NEEDED) return;

    float* MS = ws;                    // [2,16,512,512] ms
    float* C2 = ws + 8388608;          // [2,16,512,512] c2 -> later h3
    float* C9 = ws + 16777216;         // [2,64,512,512] gates; gx2 slots -> h4
    float* AR = ws + 50331648;         // arena, 10,485,760 floats
    float* s1 = AR + 0;
    float* s2 = AR + 1572864;
    float* s3 = AR + 1966080;
    float* s4 = AR + 2064384;
    float* u2 = AR + 2088960;
    float* u3 = AR + 3661824;
    float* u4 = AR + 5234688;
    float* p2    = AR + 0;
    float* c3    = AR + 2097152;
    float* p3    = AR + 6291456;
    float* c4    = AR + 7340032;
    float* p4    = AR + 8388608;
    float* c5    = AR + 8650752;
    float* p5    = AR + 8912896;
    float* c6    = AR + 8978432;
    float* u6    = AR + 9109504;
    float* t6    = AR + 0;
    float* c6re  = AR + 8388608;
    float* c7pre = AR + 524288;
    float* c7    = AR + 6291456;
    float* c8pre = AR + 0;
    float* c8    = AR + 2097152;
    float* HM  = AR + 0;
    float* SB  = AR + 8388608;   // 7 x 131072 floats (scan summaries)
    float* H3  = C2;
    float* C10 = C9;

    auto cdiv = [](int a, int b) { return (a + b - 1) / b; };

    // ---- multi-scale branch ----
    conv_k<3,3,0><<<dim3(16,32,2),256,0,stream>>>(x,3,nullptr,0,nullptr,0,nullptr,0,
                                                  w_s1,b_s1, s1, 512,512,3,1);
    pool_k<<<cdiv(2*3*256*256,256),256,0,stream>>>(s1, s2, 6, 512, 512);
    pool_k<<<cdiv(2*3*128*128,256),256,0,stream>>>(s2, s3, 6, 256, 256);
    pool_k<<<cdiv(2*3*64*64,  256),256,0,stream>>>(s3, s4, 6, 128, 128);
    up_k<<<cdiv(2*3*512*512,256),256,0,stream>>>(s2, u2, 6, 256, 256, 2);
    up_k<<<cdiv(2*3*512*512,256),256,0,stream>>>(s3, u3, 6, 128, 128, 4);
    up_k<<<cdiv(2*3*512*512,256),256,0,stream>>>(s4, u4, 6, 64, 64, 8);
    conv_k<3,16,0><<<dim3(16,32,2),256,0,stream>>>(s1,3,u2,3,u3,3,u4,3,
                                                   w_mc,b_mc, MS, 512,512,16,1);

    // ---- encoder ----
    conv_k<5,16,1><<<dim3(16,32,2),256,0,stream>>>(x,3,nullptr,0,nullptr,0,nullptr,0,
                                                   w2,b2, C2, 512,512,16,1);
    pool_k<<<cdiv(2*16*256*256,256),256,0,stream>>>(C2, p2, 32, 512, 512);
    conv_k<3,16,1><<<dim3(8,16,4),256,0,stream>>>(p2,16,nullptr,0,nullptr,0,nullptr,0,
                                                  w3,b3, c3, 256,256,32,2);
    pool_k<<<cdiv(2*32*128*128,256),256,0,stream>>>(c3, p3, 64, 256, 256);
    conv_k<3,16,1><<<dim3(4,8,4),256,0,stream>>>(p3,32,nullptr,0,nullptr,0,nullptr,0,
                                                 w4,b4, c4, 128,128,32,2);
    pool_k<<<cdiv(2*32*64*64,256),256,0,stream>>>(c4, p4, 64, 128, 128);
    conv_k<3,16,1><<<dim3(2,4,4),256,0,stream>>>(p4,32,nullptr,0,nullptr,0,nullptr,0,
                                                 w5,b5, c5, 64,64,32,2);
    pool_k<<<cdiv(2*32*32*32,256),256,0,stream>>>(c5, p5, 64, 64, 64);
    conv_k<3,16,1><<<dim3(1,2,8),256,0,stream>>>(p5,32,nullptr,0,nullptr,0,nullptr,0,
                                                 w6,b6, c6, 32,32,64,4);

    // ---- decoder ----
    up_k<<<cdiv(2*64*64*64,256),256,0,stream>>>(c6, u6, 128, 32, 32, 2);
    conv_k<3,16,1><<<dim3(2,4,8),256,0,stream>>>(u6,64,nullptr,0,nullptr,0,nullptr,0,
                                                 w6s,b6s, t6, 64,64,64,4);
    up_k<<<cdiv(2*64*128*128,256),256,0,stream>>>(t6, c6re, 128, 64, 64, 2);
    conv_k<3,16,1><<<dim3(4,8,4),256,0,stream>>>(c6re,64,c4,32,nullptr,0,nullptr,0,
                                                 w7,b7, c7pre, 128,128,32,2);
    up_k<<<cdiv(2*32*256*256,256),256,0,stream>>>(c7pre, c7, 64, 128, 128, 2);
    conv_k<3,16,1><<<dim3(8,16,2),256,0,stream>>>(c7,32,c3,32,nullptr,0,nullptr,0,
                                                  w8,b8, c8pre, 256,256,16,1);
    up_k<<<cdiv(2*16*512*512,256),256,0,stream>>>(c8pre, c8, 32, 256, 256, 2);
    conv_k<3,16,2><<<dim3(16,32,8),256,0,stream>>>(c8,16,C2,16,nullptr,0,nullptr,0,
                                                   w9,b9, C9, 512,512,64,4);

    // ---- linear recurrence scans ----
    scan_h_fused<<<4096,256,0,stream>>>(C9, MS, HM);
    sv_a<<<512,256,0,stream>>>(C9, MS, SB);
    sv_b<<<512,256,0,stream>>>(C9, MS, SB, H3);
    sv_c<<<512,256,0,stream>>>(C9, H3, SB, HM);
    sv_d<<<512,256,0,stream>>>(C9, SB, HM);

    // ---- head ----
    conv_k<3,16,1><<<dim3(16,32,8),256,0,stream>>>(HM,16,nullptr,0,nullptr,0,nullptr,0,
                                                   w10,b10, C10, 512,512,64,4);
    conv_k<3,3,1><<<dim3(16,32,2),256,0,stream>>>(C10,64,nullptr,0,nullptr,0,nullptr,0,
                                                  w11,b11, out, 512,512,3,1);
    (void)in_sizes; (void)n_in; (void)out_size; (void)ws_size;
}